// Round 1
// baseline (3352.634 us; speedup 1.0000x reference)
//
#include <hip/hip_runtime.h>

// ---------------------------------------------------------------------------
// LinearDecoder: MLP encoder -> 64-step LSTM decoder with softmax/sigmoid head
// B=8192, LAT=256, MLP=512, HID=512, INP=128, T=64, gates N=2048, K=640
// Strategy: fp16 MFMA (16x16x32) everywhere, f32 accum, C state kept f32.
// ---------------------------------------------------------------------------

typedef _Float16 h16;
typedef __attribute__((ext_vector_type(8))) _Float16 f16x8;
typedef __attribute__((ext_vector_type(4))) float f32x4;

#define BB 8192
#define TT 64

__device__ __forceinline__ void gload16(const void* g, void* lds) {
  __builtin_amdgcn_global_load_lds(
      (const __attribute__((address_space(1))) unsigned int*)g,
      (__attribute__((address_space(3))) unsigned int*)lds, 16, 0, 0);
}

__device__ __forceinline__ float sigm(float x) { return 1.f / (1.f + __expf(-x)); }
__device__ __forceinline__ float tanhf_(float x) { return 2.f / (1.f + __expf(-2.f * x)) - 1.f; }

enum { EP_LRELU = 0, EP_LIN16 = 1, EP_F32 = 2, EP_LSTM = 3 };

// Generic 128x128-tile fp16 GEMM: out = A[M,K] @ Bt^T (Bt is [N][K]) + bias
// LDS chunk-XOR swizzle: LDS(row, c) holds global 16B-chunk (c ^ (row&7)).
// EP_LSTM: Bt is the permuted gate matrix; epilogue does the LSTM cell update.
template <int EP>
__global__ __launch_bounds__(256) void gemm128(
    const h16* __restrict__ A, int lda, const h16* __restrict__ Bt,
    const float* __restrict__ bias, int K,
    h16* __restrict__ out16, int ldo, int ocol,
    float* __restrict__ outf, int ldf,
    float* __restrict__ Cbuf, h16* __restrict__ Hout) {
  __shared__ h16 As[128 * 64];
  __shared__ h16 Bs[128 * 64];
  const int tid = threadIdx.x;
  const int lane = tid & 63;
  const int w = tid >> 6;
  const int m0 = blockIdx.x * 128;
  const int n0 = blockIdx.y * 128;

  f32x4 acc[4][4];
#pragma unroll
  for (int i = 0; i < 4; ++i)
#pragma unroll
    for (int j = 0; j < 4; ++j) acc[i][j] = (f32x4)0.f;

  const int rh = (w >> 1) * 64;  // wave's row half
  const int arow = lane & 15;
  const int khi = lane >> 4;  // 0..3

  const int nkt = K >> 6;
  for (int kt = 0; kt < nkt; ++kt) {
    // stage A and B tiles (each [128 rows][64 k] fp16, 16 loads of 1KB each)
#pragma unroll
    for (int li = 0; li < 4; ++li) {
      int L = w * 4 + li;
      int r = L * 8 + (lane >> 3);
      int c = lane & 7;
      int gc = c ^ (r & 7);
      gload16(A + (size_t)(m0 + r) * lda + kt * 64 + gc * 8, &As[L * 512]);
      gload16(Bt + (size_t)(n0 + r) * K + kt * 64 + gc * 8, &Bs[L * 512]);
    }
    __syncthreads();
#pragma unroll
    for (int kk = 0; kk < 2; ++kk) {
      const int kc = kk * 4 + khi;
      f16x8 af[4], bf[4];
#pragma unroll
      for (int mt = 0; mt < 4; ++mt) {
        int r = rh + mt * 16 + arow;
        af[mt] = *(const f16x8*)&As[r * 64 + (kc ^ (r & 7)) * 8];
      }
#pragma unroll
      for (int j = 0; j < 4; ++j) {
        int nt = (EP == EP_LSTM) ? (j * 2 + (w & 1)) : ((w & 1) * 4 + j);
        int r = nt * 16 + arow;
        bf[j] = *(const f16x8*)&Bs[r * 64 + (kc ^ (r & 7)) * 8];
      }
#pragma unroll
      for (int mt = 0; mt < 4; ++mt)
#pragma unroll
        for (int j = 0; j < 4; ++j)
          acc[mt][j] =
              __builtin_amdgcn_mfma_f32_16x16x32_f16(af[mt], bf[j], acc[mt][j], 0, 0, 0);
    }
    __syncthreads();
  }

  if constexpr (EP == EP_LSTM) {
    // gate col-permutation: n' = tn*128 + q*32 + jj  <->  orig = q*512 + tn*32 + jj
    // wave owns jj = (w&1)*16 + arow; acc[mt][q] holds gate q for that jj.
    const int jj = (w & 1) * 16 + arow;
    const int j = blockIdx.y * 32 + jj;
    const float bI = bias[n0 + 0 * 32 + jj];
    const float bF = bias[n0 + 1 * 32 + jj];
    const float bG = bias[n0 + 2 * 32 + jj];
    const float bO = bias[n0 + 3 * 32 + jj];
#pragma unroll
    for (int mt = 0; mt < 4; ++mt) {
#pragma unroll
      for (int r = 0; r < 4; ++r) {
        int m = m0 + rh + mt * 16 + khi * 4 + r;
        float gi = sigm(acc[mt][0][r] + bI);
        float gf = sigm(acc[mt][1][r] + bF);
        float gg = tanhf_(acc[mt][2][r] + bG);
        float go = sigm(acc[mt][3][r] + bO);
        size_t ci = (size_t)m * 512 + j;
        float c2 = gf * Cbuf[ci] + gi * gg;
        Cbuf[ci] = c2;
        Hout[(size_t)m * 640 + 128 + j] = (h16)(go * tanhf_(c2));
      }
    }
  } else {
#pragma unroll
    for (int mt = 0; mt < 4; ++mt) {
#pragma unroll
      for (int j = 0; j < 4; ++j) {
        int nt = (w & 1) * 4 + j;
        int n = n0 + nt * 16 + arow;
        float bv = bias[n];
#pragma unroll
        for (int r = 0; r < 4; ++r) {
          int m = m0 + rh + mt * 16 + khi * 4 + r;
          float v = acc[mt][j][r] + bv;
          if constexpr (EP == EP_LRELU) {
            v = v >= 0.f ? v : 0.2f * v;
            out16[(size_t)m * ldo + n] = (h16)v;
          } else if constexpr (EP == EP_LIN16) {
            out16[(size_t)m * ldo + ocol + n] = (h16)v;
          } else {
            outf[(size_t)m * ldf + n] = v;
          }
        }
      }
    }
  }
}

// Head: L = A[M,512] @ Bt^T ([128][K]) + bias; softmax(cols 0..126), sigmoid(127).
// Writes fp16 next-x into Xout (stride 640) and optionally f32 y[b][t][:].
__global__ __launch_bounds__(256) void head_gemm(
    const h16* __restrict__ A, int lda, const h16* __restrict__ Bt,
    const float* __restrict__ bias, int K, h16* __restrict__ Xout,
    float* __restrict__ ydst, int tstep) {
  __shared__ h16 As[64 * 64];
  __shared__ h16 Bs[128 * 64];
  const int tid = threadIdx.x;
  const int lane = tid & 63;
  const int w = tid >> 6;
  const int m0 = blockIdx.x * 64;
  const int arow = lane & 15;
  const int khi = lane >> 4;

  f32x4 acc[8];
#pragma unroll
  for (int j = 0; j < 8; ++j) acc[j] = (f32x4)0.f;

  const int nkt = K >> 6;
  for (int kt = 0; kt < nkt; ++kt) {
#pragma unroll
    for (int li = 0; li < 2; ++li) {
      int L = w * 2 + li;
      int r = L * 8 + (lane >> 3);
      int c = lane & 7;
      int gc = c ^ (r & 7);
      gload16(A + (size_t)(m0 + r) * lda + kt * 64 + gc * 8, &As[L * 512]);
    }
#pragma unroll
    for (int li = 0; li < 4; ++li) {
      int L = w * 4 + li;
      int r = L * 8 + (lane >> 3);
      int c = lane & 7;
      int gc = c ^ (r & 7);
      gload16(Bt + (size_t)r * K + kt * 64 + gc * 8, &Bs[L * 512]);
    }
    __syncthreads();
#pragma unroll
    for (int kk = 0; kk < 2; ++kk) {
      int kc = kk * 4 + khi;
      int ra = w * 16 + arow;
      f16x8 af = *(const f16x8*)&As[ra * 64 + (kc ^ (ra & 7)) * 8];
#pragma unroll
      for (int nt = 0; nt < 8; ++nt) {
        int rb = nt * 16 + arow;
        f16x8 bf = *(const f16x8*)&Bs[rb * 64 + (kc ^ (rb & 7)) * 8];
        acc[nt] = __builtin_amdgcn_mfma_f32_16x16x32_f16(af, bf, acc[nt], 0, 0, 0);
      }
    }
    __syncthreads();
  }

#pragma unroll
  for (int r = 0; r < 4; ++r) {
    int m = m0 + w * 16 + khi * 4 + r;
    float v[8];
    float mx = -1e30f;
#pragma unroll
    for (int nt = 0; nt < 8; ++nt) {
      int col = nt * 16 + arow;
      v[nt] = acc[nt][r] + bias[col];
      if (col != 127) mx = fmaxf(mx, v[nt]);
    }
#pragma unroll
    for (int s = 1; s < 16; s <<= 1) mx = fmaxf(mx, __shfl_xor(mx, s, 16));
    float sm = 0.f;
#pragma unroll
    for (int nt = 0; nt < 8; ++nt) {
      int col = nt * 16 + arow;
      if (col != 127) sm += __expf(v[nt] - mx);
    }
#pragma unroll
    for (int s = 1; s < 16; s <<= 1) sm += __shfl_xor(sm, s, 16);
    float inv = 1.f / sm;
#pragma unroll
    for (int nt = 0; nt < 8; ++nt) {
      int col = nt * 16 + arow;
      float res = (col == 127) ? sigm(v[nt]) : __expf(v[nt] - mx) * inv;
      Xout[(size_t)m * 640 + col] = (h16)res;
      if (ydst) ydst[((size_t)m * 64 + tstep) * 128 + col] = res;
    }
  }
}

// ---------------- prep kernels ----------------
__global__ void cvt16(const float* __restrict__ in, h16* __restrict__ out, int n) {
  int i = blockIdx.x * 256 + threadIdx.x;
  if (i < n) out[i] = (h16)in[i];
}

// WT[n*K + k] = (h16) W[k*N + n]   (coalesced reads)
__global__ void transposeW(const float* __restrict__ W, h16* __restrict__ WT, int K,
                           int N) {
  int i = blockIdx.x * 256 + threadIdx.x;
  if (i >= K * N) return;
  int k = i / N, n = i % N;
  WT[(size_t)n * K + k] = (h16)W[i];
}

// Permuted+transposed gate matrix WgT[2048][640] and bias bg[2048].
// n' = tn*128 + q*32 + jj  ->  orig col = q*512 + tn*32 + jj, rows = [Wih; Whh].
__global__ void prep_gate(const float* __restrict__ Wih, const float* __restrict__ Whh,
                          const float* __restrict__ bih, const float* __restrict__ bhh,
                          h16* __restrict__ WgT, float* __restrict__ bg) {
  int i = blockIdx.x * 256 + threadIdx.x;
  if (i >= 2048 * 640) return;
  int np = i / 640, k = i % 640;
  int tn = np >> 7, q = (np >> 5) & 3, jj = np & 31;
  int orig = q * 512 + tn * 32 + jj;
  float wv = (k < 128) ? Wih[(size_t)k * 2048 + orig]
                       : Whh[(size_t)(k - 128) * 2048 + orig];
  WgT[i] = (h16)wv;
  if (k == 0) bg[np] = bih[orig] + bhh[orig];
}

// ---------------- launch ----------------
extern "C" void kernel_launch(void* const* d_in, const int* in_sizes, int n_in,
                              void* d_out, int out_size, void* d_ws, size_t ws_size,
                              hipStream_t stream) {
  const float* x = (const float*)d_in[0];
  const float* W1 = (const float*)d_in[1];
  const float* b1 = (const float*)d_in[2];
  const float* W2 = (const float*)d_in[3];
  const float* b2 = (const float*)d_in[4];
  const float* W3 = (const float*)d_in[5];
  const float* b3 = (const float*)d_in[6];
  const float* Wh1 = (const float*)d_in[7];
  const float* bh1 = (const float*)d_in[8];
  const float* Wh2 = (const float*)d_in[9];
  const float* bh2 = (const float*)d_in[10];
  const float* Wc1 = (const float*)d_in[11];
  const float* bc1 = (const float*)d_in[12];
  const float* Wc2 = (const float*)d_in[13];
  const float* bc2 = (const float*)d_in[14];
  const float* Wx1 = (const float*)d_in[15];
  const float* bx1 = (const float*)d_in[16];
  const float* Wx2 = (const float*)d_in[17];
  const float* bx2 = (const float*)d_in[18];
  const float* Wih = (const float*)d_in[19];
  const float* bih = (const float*)d_in[20];
  const float* Whh = (const float*)d_in[21];
  const float* bhh = (const float*)d_in[22];
  const float* Wp = (const float*)d_in[23];
  const float* bp = (const float*)d_in[24];

  char* ws = (char*)d_ws;
  size_t off = 0;
  auto take = [&](size_t bytes) -> void* {
    void* p = ws + off;
    off += (bytes + 255) & ~(size_t)255;
    return p;
  };
  h16* X16 = (h16*)take((size_t)BB * 256 * 2);
  h16* Za = (h16*)take((size_t)BB * 512 * 2);
  h16* Zb = (h16*)take((size_t)BB * 512 * 2);
  h16* XHa = (h16*)take((size_t)BB * 640 * 2);
  h16* XHb = (h16*)take((size_t)BB * 640 * 2);
  float* C = (float*)take((size_t)BB * 512 * 4);
  h16* W1T = (h16*)take(256 * 512 * 2);
  h16* W2T = (h16*)take(512 * 512 * 2);
  h16* W3T = (h16*)take(512 * 512 * 2);
  h16* Wh1T = (h16*)take(512 * 512 * 2);
  h16* Wh2T = (h16*)take(512 * 512 * 2);
  h16* Wc1T = (h16*)take(512 * 512 * 2);
  h16* Wc2T = (h16*)take(512 * 512 * 2);
  h16* Wx1T = (h16*)take(512 * 512 * 2);
  h16* Wx2T = (h16*)take(128 * 512 * 2);
  h16* WpT = (h16*)take(128 * 512 * 2);
  h16* WgT = (h16*)take((size_t)2048 * 640 * 2);
  float* bg = (float*)take(2048 * 4);

  dim3 blk(256);
  // prep
  cvt16<<<(BB * 256 + 255) / 256, blk, 0, stream>>>(x, X16, BB * 256);
  transposeW<<<(256 * 512 + 255) / 256, blk, 0, stream>>>(W1, W1T, 256, 512);
  transposeW<<<(512 * 512 + 255) / 256, blk, 0, stream>>>(W2, W2T, 512, 512);
  transposeW<<<(512 * 512 + 255) / 256, blk, 0, stream>>>(W3, W3T, 512, 512);
  transposeW<<<(512 * 512 + 255) / 256, blk, 0, stream>>>(Wh1, Wh1T, 512, 512);
  transposeW<<<(512 * 512 + 255) / 256, blk, 0, stream>>>(Wh2, Wh2T, 512, 512);
  transposeW<<<(512 * 512 + 255) / 256, blk, 0, stream>>>(Wc1, Wc1T, 512, 512);
  transposeW<<<(512 * 512 + 255) / 256, blk, 0, stream>>>(Wc2, Wc2T, 512, 512);
  transposeW<<<(512 * 512 + 255) / 256, blk, 0, stream>>>(Wx1, Wx1T, 512, 512);
  transposeW<<<(512 * 128 + 255) / 256, blk, 0, stream>>>(Wx2, Wx2T, 512, 128);
  transposeW<<<(512 * 128 + 255) / 256, blk, 0, stream>>>(Wp, WpT, 512, 128);
  prep_gate<<<(2048 * 640 + 255) / 256, blk, 0, stream>>>(Wih, Whh, bih, bhh, WgT, bg);

  // MLP encoder
  gemm128<EP_LRELU><<<dim3(64, 4), blk, 0, stream>>>(X16, 256, W1T, b1, 256, Za, 512, 0,
                                                     nullptr, 0, nullptr, nullptr);
  gemm128<EP_LRELU><<<dim3(64, 4), blk, 0, stream>>>(Za, 512, W2T, b2, 512, Zb, 512, 0,
                                                     nullptr, 0, nullptr, nullptr);
  gemm128<EP_LRELU><<<dim3(64, 4), blk, 0, stream>>>(Zb, 512, W3T, b3, 512, Za, 512, 0,
                                                     nullptr, 0, nullptr, nullptr);
  gemm128<EP_LRELU><<<dim3(64, 4), blk, 0, stream>>>(Za, 512, Wh1T, bh1, 512, Zb, 512, 0,
                                                     nullptr, 0, nullptr, nullptr);
  gemm128<EP_LIN16><<<dim3(64, 4), blk, 0, stream>>>(Zb, 512, Wh2T, bh2, 512, XHa, 640,
                                                     128, nullptr, 0, nullptr, nullptr);
  gemm128<EP_LRELU><<<dim3(64, 4), blk, 0, stream>>>(Za, 512, Wc1T, bc1, 512, Zb, 512, 0,
                                                     nullptr, 0, nullptr, nullptr);
  gemm128<EP_F32><<<dim3(64, 4), blk, 0, stream>>>(Zb, 512, Wc2T, bc2, 512, nullptr, 0, 0,
                                                   C, 512, nullptr, nullptr);
  gemm128<EP_LRELU><<<dim3(64, 4), blk, 0, stream>>>(Za, 512, Wx1T, bx1, 512, Zb, 512, 0,
                                                     nullptr, 0, nullptr, nullptr);
  head_gemm<<<128, blk, 0, stream>>>(Zb, 512, Wx2T, bx2, 512, XHa, nullptr, 0);

  // LSTM decoder
  float* yout = (float*)d_out;
  for (int t = 0; t < TT; ++t) {
    h16* in_ = (t & 1) ? XHb : XHa;
    h16* out_ = (t & 1) ? XHa : XHb;
    gemm128<EP_LSTM><<<dim3(64, 16), blk, 0, stream>>>(in_, 640, WgT, bg, 640, nullptr,
                                                       0, 0, nullptr, 0, C, out_);
    head_gemm<<<128, blk, 0, stream>>>(out_ + 128, 640, WpT, bp, 512, out_, yout, t);
  }
}

// Round 2
// 2969.578 us; speedup vs baseline: 1.1290x; 1.1290x over previous
//
#include <hip/hip_runtime.h>

// ---------------------------------------------------------------------------
// LinearDecoder: MLP encoder -> 64-step LSTM decoder with softmax/sigmoid head
// B=8192, LAT=256, MLP=512, HID=512, INP=128, T=64, gates N=2048, K=640
// fp16 MFMA 16x16x32, f32 accum; gate GEMM uses 256x256 8-phase schedule
// (T2 swizzle + T3/T4 counted vmcnt + T5 setprio), 8 waves, 128KB LDS.
// ---------------------------------------------------------------------------

typedef _Float16 h16;
typedef __attribute__((ext_vector_type(8))) _Float16 f16x8;
typedef __attribute__((ext_vector_type(4))) float f32x4;

#define BB 8192
#define TT 64

__device__ __forceinline__ void gload16(const void* g, void* lds) {
  __builtin_amdgcn_global_load_lds(
      (const __attribute__((address_space(1))) unsigned int*)g,
      (__attribute__((address_space(3))) unsigned int*)lds, 16, 0, 0);
}

__device__ __forceinline__ float sigm(float x) { return 1.f / (1.f + __expf(-x)); }
__device__ __forceinline__ float tanhf_(float x) { return 2.f / (1.f + __expf(-2.f * x)) - 1.f; }

#define MIDBAR_LG()                                        \
  do {                                                     \
    __builtin_amdgcn_s_barrier();                          \
    asm volatile("s_waitcnt lgkmcnt(0)" ::: "memory");     \
    __builtin_amdgcn_sched_barrier(0);                     \
  } while (0)
#define ENDBAR()                                           \
  do {                                                     \
    __builtin_amdgcn_s_barrier();                          \
    asm volatile("" ::: "memory");                         \
  } while (0)

// ---------------------------------------------------------------------------
// 8-phase 256x256 gate GEMM + fused LSTM cell update.
// A = XH [8192][640] fp16; Bt = WgT [2048][640] (permuted); K=640 (10 K-tiles).
// Gate col permutation: n' = by*256 + wc*64 + q*16 + jj
//                       orig = q*512 + (by*64 + wc*16 + jj)
// so lane (arow) of wave (wr,wc) owns h-col hj = by*64+wc*16+arow and
// acc[mrep][q] is gate q for that column.
// ---------------------------------------------------------------------------
__global__ __launch_bounds__(512, 2) void gate8(
    const h16* __restrict__ A, const h16* __restrict__ Bt,
    const float* __restrict__ bg, float* __restrict__ Cbuf,
    h16* __restrict__ Hout) {
  __shared__ __align__(16) h16 As[2][256 * 64];
  __shared__ __align__(16) h16 Bs[2][256 * 64];
  const int tid = threadIdx.x;
  const int lane = tid & 63;
  const int wid = tid >> 6;
  const int wr = wid >> 2, wc = wid & 3;
  const int m0 = blockIdx.x * 256;
  const int n0 = blockIdx.y * 256;
  const int arow = lane & 15, khi = lane >> 4;
  const int x7 = arow & 7;

  // stage one half-tile (128 rows x 64 k): rows h*64..+63 of each 128-row group
  auto stage = [&](h16(*dst)[256 * 64], int slot, int h, const h16* src,
                   int base, int kt) {
#pragma unroll
    for (int li = 0; li < 2; ++li) {
      int rowbase = li * 128 + h * 64 + wid * 8;  // wave-uniform, %8==0
      int row = rowbase + (lane >> 3);
      int gc = (lane & 7) ^ (lane >> 3);
      gload16(src + (size_t)(base + row) * 640 + kt * 64 + gc * 8,
              &dst[slot][rowbase * 64]);
    }
  };

  f32x4 acc[8][4];
#pragma unroll
  for (int i = 0; i < 8; ++i)
#pragma unroll
    for (int j = 0; j < 4; ++j) acc[i][j] = (f32x4)0.f;
  f16x8 af[4], bf[2][4];

  auto readA = [&](int slot, int ms, int ks) {
#pragma unroll
    for (int mr = 0; mr < 4; ++mr) {
      int r = wr * 128 + ms * 64 + mr * 16 + arow;
      af[mr] = *(const f16x8*)&As[slot][r * 64 + ((ks * 4 + khi) ^ x7) * 8];
    }
  };
  auto readB = [&](int slot, int ks) {
#pragma unroll
    for (int j = 0; j < 4; ++j) {
      int rb = wc * 64 + j * 16 + arow;
      bf[ks][j] = *(const f16x8*)&Bs[slot][rb * 64 + ((ks * 4 + khi) ^ x7) * 8];
    }
  };
  auto mfma16 = [&](int ms, int ks) {
    __builtin_amdgcn_s_setprio(1);
#pragma unroll
    for (int mr = 0; mr < 4; ++mr)
#pragma unroll
      for (int j = 0; j < 4; ++j)
        acc[ms * 4 + mr][j] = __builtin_amdgcn_mfma_f32_16x16x32_f16(
            af[mr], bf[ks][j], acc[ms * 4 + mr][j], 0, 0, 0);
    __builtin_amdgcn_s_setprio(0);
  };

  // prologue: kt0 fully, kt1 all but A-h1
  stage(Bs, 0, 0, Bt, n0, 0);
  stage(Bs, 0, 1, Bt, n0, 0);
  stage(As, 0, 0, A, m0, 0);
  stage(As, 0, 1, A, m0, 0);
  stage(Bs, 1, 0, Bt, n0, 1);
  stage(Bs, 1, 1, Bt, n0, 1);
  stage(As, 1, 0, A, m0, 1);
  asm volatile("s_waitcnt vmcnt(6)" ::: "memory");
  ENDBAR();

#pragma unroll 1
  for (int i = 0; i < 5; ++i) {
    const int t2 = 2 * i + 2, t3 = 2 * i + 3;
    // P1: slot0 (ms0,ks0); 12 ds_reads; stage A-h1(kt+1)
    readB(0, 0);
    readB(0, 1);
    readA(0, 0, 0);
    stage(As, 1, 1, A, m0, 2 * i + 1);
    MIDBAR_LG();
    mfma16(0, 0);
    ENDBAR();
    // P2: (ms0,ks1); stage B-h0(t2)
    readA(0, 0, 1);
    if (t2 < 10) stage(Bs, 0, 0, Bt, n0, t2);
    MIDBAR_LG();
    mfma16(0, 1);
    ENDBAR();
    // P3: (ms1,ks0); stage B-h1(t2)
    readA(0, 1, 0);
    if (t2 < 10) stage(Bs, 0, 1, Bt, n0, t2);
    MIDBAR_LG();
    mfma16(1, 0);
    ENDBAR();
    // P4: (ms1,ks1); stage A-h0(t2); counted vmcnt
    readA(0, 1, 1);
    if (t2 < 10) stage(As, 0, 0, A, m0, t2);
    if (i < 4)
      asm volatile("s_waitcnt vmcnt(6)" ::: "memory");
    else
      asm volatile("s_waitcnt vmcnt(0)" ::: "memory");
    MIDBAR_LG();
    mfma16(1, 1);
    ENDBAR();
    // P5: slot1 (ms0,ks0); 12 ds_reads; stage A-h1(t2)
    readB(1, 0);
    readB(1, 1);
    readA(1, 0, 0);
    if (t2 < 10) stage(As, 0, 1, A, m0, t2);
    MIDBAR_LG();
    mfma16(0, 0);
    ENDBAR();
    // P6: (ms0,ks1); stage B-h0(t3)
    readA(1, 0, 1);
    if (t3 < 10) stage(Bs, 1, 0, Bt, n0, t3);
    MIDBAR_LG();
    mfma16(0, 1);
    ENDBAR();
    // P7: (ms1,ks0); stage B-h1(t3)
    readA(1, 1, 0);
    if (t3 < 10) stage(Bs, 1, 1, Bt, n0, t3);
    MIDBAR_LG();
    mfma16(1, 0);
    ENDBAR();
    // P8: (ms1,ks1); stage A-h0(t3); counted vmcnt
    readA(1, 1, 1);
    if (t3 < 10) stage(As, 1, 0, A, m0, t3);
    if (i < 4)
      asm volatile("s_waitcnt vmcnt(6)" ::: "memory");
    else
      asm volatile("s_waitcnt vmcnt(0)" ::: "memory");
    MIDBAR_LG();
    mfma16(1, 1);
    ENDBAR();
  }

  // epilogue: LSTM cell update. lane owns h-col hj; acc[mrep][q] = gate q.
  const int hj = blockIdx.y * 64 + wc * 16 + arow;
  const int nb = n0 + wc * 64;
  const float bI = bg[nb + arow];
  const float bF = bg[nb + 16 + arow];
  const float bG = bg[nb + 32 + arow];
  const float bO = bg[nb + 48 + arow];
#pragma unroll
  for (int mrep = 0; mrep < 8; ++mrep) {
#pragma unroll
    for (int r = 0; r < 4; ++r) {
      int m = m0 + wr * 128 + mrep * 16 + khi * 4 + r;
      float gi = sigm(acc[mrep][0][r] + bI);
      float gf = sigm(acc[mrep][1][r] + bF);
      float gg = tanhf_(acc[mrep][2][r] + bG);
      float go = sigm(acc[mrep][3][r] + bO);
      size_t ci = (size_t)m * 512 + hj;
      float c2 = gf * Cbuf[ci] + gi * gg;
      Cbuf[ci] = c2;
      Hout[(size_t)m * 640 + 128 + hj] = (h16)(go * tanhf_(c2));
    }
  }
}

// ---------------------------------------------------------------------------
// Head: L = A[M,512] @ Bt^T ([128][512]) + bias; softmax(0..126), sigmoid(127).
// 2-phase double-buffered staging with counted vmcnt(6).
// ---------------------------------------------------------------------------
__global__ __launch_bounds__(256) void head_gemm2(
    const h16* __restrict__ A, int lda, const h16* __restrict__ Bt,
    const float* __restrict__ bias, int nkt, h16* __restrict__ Xout,
    float* __restrict__ ydst, int tstep) {
  __shared__ __align__(16) h16 As[2][64 * 64];
  __shared__ __align__(16) h16 Bs[2][128 * 64];
  const int tid = threadIdx.x;
  const int lane = tid & 63;
  const int w = tid >> 6;
  const int m0 = blockIdx.x * 64;
  const int arow = lane & 15, khi = lane >> 4;
  const int x7 = arow & 7;

  auto stageA = [&](int slot, int kt) {
#pragma unroll
    for (int li = 0; li < 2; ++li) {
      int rowbase = li * 32 + w * 8;
      int row = rowbase + (lane >> 3);
      int gc = (lane & 7) ^ (lane >> 3);
      gload16(A + (size_t)(m0 + row) * lda + kt * 64 + gc * 8,
              &As[slot][rowbase * 64]);
    }
  };
  auto stageB = [&](int slot, int kt) {
#pragma unroll
    for (int li = 0; li < 4; ++li) {
      int rowbase = li * 32 + w * 8;
      int row = rowbase + (lane >> 3);
      int gc = (lane & 7) ^ (lane >> 3);
      gload16(Bt + (size_t)row * 512 + kt * 64 + gc * 8,
              &Bs[slot][rowbase * 64]);
    }
  };

  f32x4 acc[8];
#pragma unroll
  for (int j = 0; j < 8; ++j) acc[j] = (f32x4)0.f;

  stageA(0, 0);
  stageB(0, 0);
#pragma unroll 1
  for (int kt = 0; kt < nkt; ++kt) {
    int p = kt & 1;
    if (kt + 1 < nkt) {
      stageA(p ^ 1, kt + 1);
      stageB(p ^ 1, kt + 1);
      asm volatile("s_waitcnt vmcnt(6)" ::: "memory");
    } else {
      asm volatile("s_waitcnt vmcnt(0)" ::: "memory");
    }
    ENDBAR();
#pragma unroll
    for (int kk = 0; kk < 2; ++kk) {
      int kc = kk * 4 + khi;
      int ra = w * 16 + arow;
      f16x8 afr = *(const f16x8*)&As[p][ra * 64 + (kc ^ x7) * 8];
#pragma unroll
      for (int nt = 0; nt < 8; ++nt) {
        int rb = nt * 16 + arow;
        f16x8 bfr = *(const f16x8*)&Bs[p][rb * 64 + (kc ^ x7) * 8];
        acc[nt] = __builtin_amdgcn_mfma_f32_16x16x32_f16(afr, bfr, acc[nt], 0, 0, 0);
      }
    }
    ENDBAR();
  }

#pragma unroll
  for (int r = 0; r < 4; ++r) {
    int m = m0 + w * 16 + khi * 4 + r;
    float v[8];
    float mx = -1e30f;
#pragma unroll
    for (int nt = 0; nt < 8; ++nt) {
      int col = nt * 16 + arow;
      v[nt] = acc[nt][r] + bias[col];
      if (col != 127) mx = fmaxf(mx, v[nt]);
    }
#pragma unroll
    for (int s = 1; s < 16; s <<= 1) mx = fmaxf(mx, __shfl_xor(mx, s, 16));
    float sm = 0.f;
#pragma unroll
    for (int nt = 0; nt < 8; ++nt) {
      int col = nt * 16 + arow;
      if (col != 127) sm += __expf(v[nt] - mx);
    }
#pragma unroll
    for (int s = 1; s < 16; s <<= 1) sm += __shfl_xor(sm, s, 16);
    float inv = 1.f / sm;
#pragma unroll
    for (int nt = 0; nt < 8; ++nt) {
      int col = nt * 16 + arow;
      float res = (col == 127) ? sigm(v[nt]) : __expf(v[nt] - mx) * inv;
      Xout[(size_t)m * 640 + col] = (h16)res;
      if (ydst) ydst[((size_t)m * 64 + tstep) * 128 + col] = res;
    }
  }
}

// ---------------------------------------------------------------------------
// Encoder GEMM (verified round-1 structure, 128x128 tile)
// ---------------------------------------------------------------------------
enum { EP_LRELU = 0, EP_LIN16 = 1, EP_F32 = 2 };

template <int EP>
__global__ __launch_bounds__(256) void gemm128(
    const h16* __restrict__ A, int lda, const h16* __restrict__ Bt,
    const float* __restrict__ bias, int K, h16* __restrict__ out16, int ldo,
    int ocol, float* __restrict__ outf, int ldf) {
  __shared__ __align__(16) h16 As[128 * 64];
  __shared__ __align__(16) h16 Bs[128 * 64];
  const int tid = threadIdx.x;
  const int lane = tid & 63;
  const int w = tid >> 6;
  const int m0 = blockIdx.x * 128;
  const int n0 = blockIdx.y * 128;

  f32x4 acc[4][4];
#pragma unroll
  for (int i = 0; i < 4; ++i)
#pragma unroll
    for (int j = 0; j < 4; ++j) acc[i][j] = (f32x4)0.f;

  const int rh = (w >> 1) * 64;
  const int arow = lane & 15;
  const int khi = lane >> 4;

  const int nkt = K >> 6;
  for (int kt = 0; kt < nkt; ++kt) {
#pragma unroll
    for (int li = 0; li < 4; ++li) {
      int L = w * 4 + li;
      int r = L * 8 + (lane >> 3);
      int c = lane & 7;
      int gc = c ^ (r & 7);
      gload16(A + (size_t)(m0 + r) * lda + kt * 64 + gc * 8, &As[L * 512]);
      gload16(Bt + (size_t)(n0 + r) * K + kt * 64 + gc * 8, &Bs[L * 512]);
    }
    __syncthreads();
#pragma unroll
    for (int kk = 0; kk < 2; ++kk) {
      const int kc = kk * 4 + khi;
      f16x8 af[4], bf[4];
#pragma unroll
      for (int mt = 0; mt < 4; ++mt) {
        int r = rh + mt * 16 + arow;
        af[mt] = *(const f16x8*)&As[r * 64 + (kc ^ (r & 7)) * 8];
      }
#pragma unroll
      for (int j = 0; j < 4; ++j) {
        int nt = (w & 1) * 4 + j;
        int r = nt * 16 + arow;
        bf[j] = *(const f16x8*)&Bs[r * 64 + (kc ^ (r & 7)) * 8];
      }
#pragma unroll
      for (int mt = 0; mt < 4; ++mt)
#pragma unroll
        for (int j = 0; j < 4; ++j)
          acc[mt][j] =
              __builtin_amdgcn_mfma_f32_16x16x32_f16(af[mt], bf[j], acc[mt][j], 0, 0, 0);
    }
    __syncthreads();
  }

#pragma unroll
  for (int mt = 0; mt < 4; ++mt) {
#pragma unroll
    for (int j = 0; j < 4; ++j) {
      int nt = (w & 1) * 4 + j;
      int n = n0 + nt * 16 + arow;
      float bv = bias[n];
#pragma unroll
      for (int r = 0; r < 4; ++r) {
        int m = m0 + rh + mt * 16 + khi * 4 + r;
        float v = acc[mt][j][r] + bv;
        if constexpr (EP == EP_LRELU) {
          v = v >= 0.f ? v : 0.2f * v;
          out16[(size_t)m * ldo + n] = (h16)v;
        } else if constexpr (EP == EP_LIN16) {
          out16[(size_t)m * ldo + ocol + n] = (h16)v;
        } else {
          outf[(size_t)m * ldf + n] = v;
        }
      }
    }
  }
}

// ---------------- prep kernels ----------------
__global__ void cvt16(const float* __restrict__ in, h16* __restrict__ out, int n) {
  int i = blockIdx.x * 256 + threadIdx.x;
  if (i < n) out[i] = (h16)in[i];
}

__global__ void transposeW(const float* __restrict__ W, h16* __restrict__ WT, int K,
                           int N) {
  int i = blockIdx.x * 256 + threadIdx.x;
  if (i >= K * N) return;
  int k = i / N, n = i % N;
  WT[(size_t)n * K + k] = (h16)W[i];
}

// WgT[n'][640]: n' = by*256 + wc*64 + q*16 + jj -> orig = q*512 + by*64 + wc*16 + jj
__global__ void prep_gate(const float* __restrict__ Wih, const float* __restrict__ Whh,
                          const float* __restrict__ bih, const float* __restrict__ bhh,
                          h16* __restrict__ WgT, float* __restrict__ bg) {
  int i = blockIdx.x * 256 + threadIdx.x;
  if (i >= 2048 * 640) return;
  int np = i / 640, k = i % 640;
  int by = np >> 8, wcc = (np >> 6) & 3, q = (np >> 4) & 3, jj = np & 15;
  int orig = q * 512 + by * 64 + wcc * 16 + jj;
  float wv = (k < 128) ? Wih[(size_t)k * 2048 + orig]
                       : Whh[(size_t)(k - 128) * 2048 + orig];
  WgT[i] = (h16)wv;
  if (k == 0) bg[np] = bih[orig] + bhh[orig];
}

// ---------------- launch ----------------
extern "C" void kernel_launch(void* const* d_in, const int* in_sizes, int n_in,
                              void* d_out, int out_size, void* d_ws, size_t ws_size,
                              hipStream_t stream) {
  const float* x = (const float*)d_in[0];
  const float* W1 = (const float*)d_in[1];
  const float* b1 = (const float*)d_in[2];
  const float* W2 = (const float*)d_in[3];
  const float* b2 = (const float*)d_in[4];
  const float* W3 = (const float*)d_in[5];
  const float* b3 = (const float*)d_in[6];
  const float* Wh1 = (const float*)d_in[7];
  const float* bh1 = (const float*)d_in[8];
  const float* Wh2 = (const float*)d_in[9];
  const float* bh2 = (const float*)d_in[10];
  const float* Wc1 = (const float*)d_in[11];
  const float* bc1 = (const float*)d_in[12];
  const float* Wc2 = (const float*)d_in[13];
  const float* bc2 = (const float*)d_in[14];
  const float* Wx1 = (const float*)d_in[15];
  const float* bx1 = (const float*)d_in[16];
  const float* Wx2 = (const float*)d_in[17];
  const float* bx2 = (const float*)d_in[18];
  const float* Wih = (const float*)d_in[19];
  const float* bih = (const float*)d_in[20];
  const float* Whh = (const float*)d_in[21];
  const float* bhh = (const float*)d_in[22];
  const float* Wp = (const float*)d_in[23];
  const float* bp = (const float*)d_in[24];

  char* ws = (char*)d_ws;
  size_t off = 0;
  auto take = [&](size_t bytes) -> void* {
    void* p = ws + off;
    off += (bytes + 255) & ~(size_t)255;
    return p;
  };
  h16* X16 = (h16*)take((size_t)BB * 256 * 2);
  h16* Za = (h16*)take((size_t)BB * 512 * 2);
  h16* Zb = (h16*)take((size_t)BB * 512 * 2);
  h16* XHa = (h16*)take((size_t)BB * 640 * 2);
  h16* XHb = (h16*)take((size_t)BB * 640 * 2);
  float* C = (float*)take((size_t)BB * 512 * 4);
  h16* W1T = (h16*)take(256 * 512 * 2);
  h16* W2T = (h16*)take(512 * 512 * 2);
  h16* W3T = (h16*)take(512 * 512 * 2);
  h16* Wh1T = (h16*)take(512 * 512 * 2);
  h16* Wh2T = (h16*)take(512 * 512 * 2);
  h16* Wc1T = (h16*)take(512 * 512 * 2);
  h16* Wc2T = (h16*)take(512 * 512 * 2);
  h16* Wx1T = (h16*)take(512 * 512 * 2);
  h16* Wx2T = (h16*)take(128 * 512 * 2);
  h16* WpT = (h16*)take(128 * 512 * 2);
  h16* WgT = (h16*)take((size_t)2048 * 640 * 2);
  float* bg = (float*)take(2048 * 4);

  dim3 blk(256);
  cvt16<<<(BB * 256 + 255) / 256, blk, 0, stream>>>(x, X16, BB * 256);
  transposeW<<<(256 * 512 + 255) / 256, blk, 0, stream>>>(W1, W1T, 256, 512);
  transposeW<<<(512 * 512 + 255) / 256, blk, 0, stream>>>(W2, W2T, 512, 512);
  transposeW<<<(512 * 512 + 255) / 256, blk, 0, stream>>>(W3, W3T, 512, 512);
  transposeW<<<(512 * 512 + 255) / 256, blk, 0, stream>>>(Wh1, Wh1T, 512, 512);
  transposeW<<<(512 * 512 + 255) / 256, blk, 0, stream>>>(Wh2, Wh2T, 512, 512);
  transposeW<<<(512 * 512 + 255) / 256, blk, 0, stream>>>(Wc1, Wc1T, 512, 512);
  transposeW<<<(512 * 512 + 255) / 256, blk, 0, stream>>>(Wc2, Wc2T, 512, 512);
  transposeW<<<(512 * 512 + 255) / 256, blk, 0, stream>>>(Wx1, Wx1T, 512, 512);
  transposeW<<<(512 * 128 + 255) / 256, blk, 0, stream>>>(Wx2, Wx2T, 512, 128);
  transposeW<<<(512 * 128 + 255) / 256, blk, 0, stream>>>(Wp, WpT, 512, 128);
  prep_gate<<<(2048 * 640 + 255) / 256, blk, 0, stream>>>(Wih, Whh, bih, bhh, WgT, bg);

  // MLP encoder
  gemm128<EP_LRELU><<<dim3(64, 4), blk, 0, stream>>>(X16, 256, W1T, b1, 256, Za, 512, 0, nullptr, 0);
  gemm128<EP_LRELU><<<dim3(64, 4), blk, 0, stream>>>(Za, 512, W2T, b2, 512, Zb, 512, 0, nullptr, 0);
  gemm128<EP_LRELU><<<dim3(64, 4), blk, 0, stream>>>(Zb, 512, W3T, b3, 512, Za, 512, 0, nullptr, 0);
  gemm128<EP_LRELU><<<dim3(64, 4), blk, 0, stream>>>(Za, 512, Wh1T, bh1, 512, Zb, 512, 0, nullptr, 0);
  gemm128<EP_LIN16><<<dim3(64, 4), blk, 0, stream>>>(Zb, 512, Wh2T, bh2, 512, XHa, 640, 128, nullptr, 0);
  gemm128<EP_LRELU><<<dim3(64, 4), blk, 0, stream>>>(Za, 512, Wc1T, bc1, 512, Zb, 512, 0, nullptr, 0);
  gemm128<EP_F32><<<dim3(64, 4), blk, 0, stream>>>(Zb, 512, Wc2T, bc2, 512, nullptr, 0, 0, C, 512);
  gemm128<EP_LRELU><<<dim3(64, 4), blk, 0, stream>>>(Za, 512, Wx1T, bx1, 512, Zb, 512, 0, nullptr, 0);
  head_gemm2<<<128, blk, 0, stream>>>(Zb, 512, Wx2T, bx2, 8, XHa, nullptr, 0);

  // LSTM decoder
  float* yout = (float*)d_out;
  for (int t = 0; t < TT; ++t) {
    h16* in_ = (t & 1) ? XHb : XHa;
    h16* out_ = (t & 1) ? XHa : XHb;
    gate8<<<dim3(32, 8), dim3(512), 0, stream>>>(in_, WgT, bg, C, out_);
    head_gemm2<<<128, blk, 0, stream>>>(out_ + 128, 640, WpT, bp, 8, out_, yout, t);
  }
}